// Round 1
// baseline (517.898 us; speedup 1.0000x reference)
//
#include <hip/hip_runtime.h>
#include <hip/hip_bf16.h>

#define BB 2
#define SS 2048
#define DD 2048
#define HH 16
#define DHH 128
#define MM 4096      // B*S
#define NN1 6144     // 3*D

typedef __attribute__((ext_vector_type(8))) short bf16x8;
typedef __attribute__((ext_vector_type(4))) float f32x4;
typedef unsigned int u32;

static __device__ __forceinline__ unsigned short f2bf(float f) {
  union { float f; u32 u; } v; v.f = f;
  return (unsigned short)((v.u + 0x7FFFu + ((v.u >> 16) & 1u)) >> 16);
}

static __device__ __forceinline__ void gload_lds16(const void* g, void* l) {
  __builtin_amdgcn_global_load_lds((const __attribute__((address_space(1))) u32*)g,
                                   (__attribute__((address_space(3))) u32*)l, 16, 0, 0);
}

// f32 -> bf16 elementwise, 4 elems/thread
__global__ __launch_bounds__(256) void k_cvt(const float* __restrict__ in,
                                             unsigned short* __restrict__ out) {
  int i = blockIdx.x * 256 + threadIdx.x;
  float4 v = ((const float4*)in)[i];
  ushort4 o;
  o.x = f2bf(v.x); o.y = f2bf(v.y); o.z = f2bf(v.z); o.w = f2bf(v.w);
  ((ushort4*)out)[i] = o;
}

// transpose f32 [R][C] -> bf16 [C][R]
__global__ __launch_bounds__(256) void k_transpose(const float* __restrict__ in,
                                                   unsigned short* __restrict__ out,
                                                   int R, int C) {
  __shared__ float t[32][33];
  int bx = blockIdx.x * 32, by = blockIdx.y * 32;
  int tx = threadIdx.x, ty = threadIdx.y;
  #pragma unroll
  for (int i = ty; i < 32; i += 8)
    t[i][tx] = in[(size_t)(by + i) * C + bx + tx];
  __syncthreads();
  #pragma unroll
  for (int i = ty; i < 32; i += 8)
    out[(size_t)(bx + i) * R + by + tx] = f2bf(t[tx][i]);
}

// ---- GEMM1: C = x(bf16)[M][K] * Wqkv^T(bf16)[N][K] + bqkv, scatter to Q/K/Vt ----
// m97 structure: 128x128 tile, BK=32, 4 waves (2x2), 4x4 16x16 frags per wave.
__global__ __launch_bounds__(256) void k_gemm1(const unsigned short* __restrict__ A,
                                               const unsigned short* __restrict__ Bt,
                                               const float* __restrict__ bias,
                                               unsigned short* __restrict__ Qb,
                                               unsigned short* __restrict__ Kb,
                                               unsigned short* __restrict__ Vt) {
  __shared__ __align__(16) unsigned short At[128 * 32];
  __shared__ __align__(16) unsigned short Bs[128 * 32];
  const int tid = threadIdx.x;
  const int wave = tid >> 6, lane = tid & 63;
  const int m0 = blockIdx.y * 128, n0 = blockIdx.x * 128;
  const int wr = wave >> 1, wc = wave & 1;
  const int lrow = lane & 15, lk = (lane >> 4) << 3;
  f32x4 acc[4][4] = {};
  for (int k0 = 0; k0 < DD; k0 += 32) {
    __syncthreads();
    #pragma unroll
    for (int r = 0; r < 2; ++r) {
      int f = r * 256 + tid;
      int row = f >> 2, col = (f & 3) << 3;
      gload_lds16(A + (size_t)(m0 + row) * DD + k0 + col, (char*)At + r * 4096 + wave * 1024);
      gload_lds16(Bt + (size_t)(n0 + row) * DD + k0 + col, (char*)Bs + r * 4096 + wave * 1024);
    }
    __syncthreads();
    bf16x8 af[4], bfv[4];
    #pragma unroll
    for (int i = 0; i < 4; ++i)
      af[i] = *(const bf16x8*)(At + (wr * 64 + i * 16 + lrow) * 32 + lk);
    #pragma unroll
    for (int j = 0; j < 4; ++j)
      bfv[j] = *(const bf16x8*)(Bs + (wc * 64 + j * 16 + lrow) * 32 + lk);
    #pragma unroll
    for (int i = 0; i < 4; ++i)
      #pragma unroll
      for (int j = 0; j < 4; ++j)
        acc[i][j] = __builtin_amdgcn_mfma_f32_16x16x32_bf16(af[i], bfv[j], acc[i][j], 0, 0, 0);
  }
  // n-tile of 128 == exactly one (which, head) pair
  const int head = (n0 >> 7) & 15, which = n0 >> 11;
  #pragma unroll
  for (int i = 0; i < 4; ++i) {
    int rowb = m0 + wr * 64 + i * 16 + ((lane >> 4) << 2);   // global token; +rg for regs
    int bb = rowb >> 11, s = rowb & 2047;                    // rows rg..rg+3 stay in same b
    #pragma unroll
    for (int j = 0; j < 4; ++j) {
      int gcol = n0 + wc * 64 + j * 16 + (lane & 15);
      int dh = gcol & 127;
      float bv = bias[gcol];
      if (which == 2) {
        // V stored transposed: Vt[b][h][dh][s]; regs are 4 consecutive s -> 8B store
        ushort4 p;
        p.x = f2bf(acc[i][j][0] + bv);
        p.y = f2bf(acc[i][j][1] + bv);
        p.z = f2bf(acc[i][j][2] + bv);
        p.w = f2bf(acc[i][j][3] + bv);
        *(ushort4*)(Vt + ((size_t)(bb * HH + head) * DHH + dh) * SS + s) = p;
      } else {
        unsigned short* dst = (which == 0 ? Qb : Kb) + ((size_t)(bb * HH + head) * SS + s) * DHH + dh;
        dst[0]       = f2bf(acc[i][j][0] + bv);
        dst[DHH]     = f2bf(acc[i][j][1] + bv);
        dst[2 * DHH] = f2bf(acc[i][j][2] + bv);
        dst[3 * DHH] = f2bf(acc[i][j][3] + bv);
      }
    }
  }
}

// ---- flash attention: 1 block = (b,h) x 64 q rows; 4 waves x 16 rows; KV tiles of 32 ----
__global__ __launch_bounds__(256) void k_attn(const unsigned short* __restrict__ Qb,
                                              const unsigned short* __restrict__ Kb,
                                              const unsigned short* __restrict__ Vt,
                                              unsigned short* __restrict__ O) {
  __shared__ __align__(16) unsigned short Kt[32 * 128];   // [kv][dh]
  __shared__ __align__(16) unsigned short Vs[128 * 32];   // [dh][kv]  (V^T tile)
  __shared__ __align__(16) unsigned short Pl[4][16 * 32]; // per-wave P [row][kv]
  const int qt = blockIdx.x, bh = blockIdx.y;
  const int b = bh >> 4, h = bh & 15;
  const int tid = threadIdx.x, wave = tid >> 6, lane = tid & 63;
  const int q0 = qt * 64 + wave * 16;
  const unsigned short* Qp = Qb + (size_t)bh * SS * DHH;
  const unsigned short* Kp = Kb + (size_t)bh * SS * DHH;
  const unsigned short* Vp = Vt + (size_t)bh * DHH * SS;
  const int lrow = lane & 15, lk = (lane >> 4) << 3;

  bf16x8 qf[4];
  #pragma unroll
  for (int ks = 0; ks < 4; ++ks)
    qf[ks] = *(const bf16x8*)(Qp + (size_t)(q0 + lrow) * DHH + ks * 32 + lk);

  f32x4 acc[8] = {};
  float mrow[4], lsum[4];
  #pragma unroll
  for (int r = 0; r < 4; ++r) { mrow[r] = -1e30f; lsum[r] = 0.f; }
  const float scale = 0.08838834764831845f;  // 1/sqrt(128)
  const int ntiles = qt * 2 + 2;             // causal: only tiles with kv0 <= q_end

  for (int t = 0; t < ntiles; ++t) {
    const int kv0 = t * 32;
    __syncthreads();
    #pragma unroll
    for (int r = 0; r < 2; ++r) {
      int f = r * 256 + tid;
      gload_lds16(Kp + (size_t)(kv0 + (f >> 4)) * DHH + ((f & 15) << 3),
                  (char*)Kt + r * 4096 + wave * 1024);
      gload_lds16(Vp + (size_t)(f >> 2) * SS + kv0 + ((f & 3) << 3),
                  (char*)Vs + r * 4096 + wave * 1024);
    }
    __syncthreads();
    if (kv0 <= q0 + 15) {            // wave-uniform causal skip
      f32x4 sa[2] = {};
      #pragma unroll
      for (int nb = 0; nb < 2; ++nb)
        #pragma unroll
        for (int ks = 0; ks < 4; ++ks) {
          bf16x8 kf = *(const bf16x8*)(Kt + (nb * 16 + lrow) * 128 + ks * 32 + lk);
          sa[nb] = __builtin_amdgcn_mfma_f32_16x16x32_bf16(qf[ks], kf, sa[nb], 0, 0, 0);
        }
      // C/D layout: col = kv0 + nb*16 + (lane&15); row = q0 + (lane>>4)*4 + r
      float p[2][4], tm[4], rs[4], sf[4];
      const int rq = q0 + ((lane >> 4) << 2);
      const int c0 = kv0 + (lane & 15);
      #pragma unroll
      for (int r = 0; r < 4; ++r) {
        float s0 = sa[0][r] * scale, s1 = sa[1][r] * scale;
        if (c0 > rq + r) s0 = -1e30f;
        if (c0 + 16 > rq + r) s1 = -1e30f;
        p[0][r] = s0; p[1][r] = s1;
        tm[r] = fmaxf(s0, s1);
      }
      #pragma unroll
      for (int off = 1; off < 16; off <<= 1)
        #pragma unroll
        for (int r = 0; r < 4; ++r)
          tm[r] = fmaxf(tm[r], __shfl_xor(tm[r], off, 64));
      #pragma unroll
      for (int r = 0; r < 4; ++r) {
        float mnew = fmaxf(mrow[r], tm[r]);
        sf[r] = __expf(mrow[r] - mnew);
        mrow[r] = mnew;
        p[0][r] = __expf(p[0][r] - mnew);
        p[1][r] = __expf(p[1][r] - mnew);
        rs[r] = p[0][r] + p[1][r];
      }
      #pragma unroll
      for (int off = 1; off < 16; off <<= 1)
        #pragma unroll
        for (int r = 0; r < 4; ++r)
          rs[r] += __shfl_xor(rs[r], off, 64);
      #pragma unroll
      for (int r = 0; r < 4; ++r) lsum[r] = lsum[r] * sf[r] + rs[r];
      #pragma unroll
      for (int nf = 0; nf < 8; ++nf)
        #pragma unroll
        for (int r = 0; r < 4; ++r) acc[nf][r] *= sf[r];
      // P (C/D layout) -> LDS -> A-fragment layout
      unsigned short* P = Pl[wave];
      #pragma unroll
      for (int r = 0; r < 4; ++r) {
        int row = ((lane >> 4) << 2) + r;
        P[row * 32 + (lane & 15)]      = f2bf(p[0][r]);
        P[row * 32 + 16 + (lane & 15)] = f2bf(p[1][r]);
      }
      asm volatile("s_waitcnt lgkmcnt(0)" ::: "memory");  // order cross-lane LDS (TBAA-proof)
      bf16x8 pf = *(const bf16x8*)(P + lrow * 32 + lk);
      #pragma unroll
      for (int nf = 0; nf < 8; ++nf) {
        bf16x8 vf = *(const bf16x8*)(Vs + (nf * 16 + lrow) * 32 + lk);
        acc[nf] = __builtin_amdgcn_mfma_f32_16x16x32_bf16(pf, vf, acc[nf], 0, 0, 0);
      }
    }
  }
  #pragma unroll
  for (int r = 0; r < 4; ++r) lsum[r] = 1.0f / lsum[r];
  unsigned short* Op = O + ((size_t)b * SS) * DD + (size_t)h * DHH;
  #pragma unroll
  for (int nf = 0; nf < 8; ++nf)
    #pragma unroll
    for (int r = 0; r < 4; ++r) {
      int q = q0 + ((lane >> 4) << 2) + r;
      Op[(size_t)q * DD + nf * 16 + (lane & 15)] = f2bf(acc[nf][r] * lsum[r]);
    }
}

// ---- GEMM2: out = O(bf16)[M][D] * Wproj^T(bf16)[D][D] + bproj, f32 out ----
__global__ __launch_bounds__(256) void k_gemm2(const unsigned short* __restrict__ A,
                                               const unsigned short* __restrict__ Bt,
                                               const float* __restrict__ bias,
                                               float* __restrict__ out) {
  __shared__ __align__(16) unsigned short At[128 * 32];
  __shared__ __align__(16) unsigned short Bs[128 * 32];
  const int tid = threadIdx.x;
  const int wave = tid >> 6, lane = tid & 63;
  const int m0 = blockIdx.y * 128, n0 = blockIdx.x * 128;
  const int wr = wave >> 1, wc = wave & 1;
  const int lrow = lane & 15, lk = (lane >> 4) << 3;
  f32x4 acc[4][4] = {};
  for (int k0 = 0; k0 < DD; k0 += 32) {
    __syncthreads();
    #pragma unroll
    for (int r = 0; r < 2; ++r) {
      int f = r * 256 + tid;
      int row = f >> 2, col = (f & 3) << 3;
      gload_lds16(A + (size_t)(m0 + row) * DD + k0 + col, (char*)At + r * 4096 + wave * 1024);
      gload_lds16(Bt + (size_t)(n0 + row) * DD + k0 + col, (char*)Bs + r * 4096 + wave * 1024);
    }
    __syncthreads();
    bf16x8 af[4], bfv[4];
    #pragma unroll
    for (int i = 0; i < 4; ++i)
      af[i] = *(const bf16x8*)(At + (wr * 64 + i * 16 + lrow) * 32 + lk);
    #pragma unroll
    for (int j = 0; j < 4; ++j)
      bfv[j] = *(const bf16x8*)(Bs + (wc * 64 + j * 16 + lrow) * 32 + lk);
    #pragma unroll
    for (int i = 0; i < 4; ++i)
      #pragma unroll
      for (int j = 0; j < 4; ++j)
        acc[i][j] = __builtin_amdgcn_mfma_f32_16x16x32_bf16(af[i], bfv[j], acc[i][j], 0, 0, 0);
  }
  #pragma unroll
  for (int i = 0; i < 4; ++i) {
    int rowb = m0 + wr * 64 + i * 16 + ((lane >> 4) << 2);
    #pragma unroll
    for (int j = 0; j < 4; ++j) {
      int gcol = n0 + wc * 64 + j * 16 + (lane & 15);
      float bv = bias[gcol];
      #pragma unroll
      for (int rg = 0; rg < 4; ++rg)
        out[(size_t)(rowb + rg) * DD + gcol] = acc[i][j][rg] + bv;
    }
  }
}

extern "C" void kernel_launch(void* const* d_in, const int* in_sizes, int n_in,
                              void* d_out, int out_size, void* d_ws, size_t ws_size,
                              hipStream_t stream) {
  const float* x     = (const float*)d_in[0];
  const float* Wqkv  = (const float*)d_in[1];
  const float* bqkv  = (const float*)d_in[2];
  const float* Wproj = (const float*)d_in[3];
  const float* bproj = (const float*)d_in[4];
  float* out = (float*)d_out;

  char* ws = (char*)d_ws;
  unsigned short* xb  = (unsigned short*)ws; ws += (size_t)MM * DD * 2;          // 16 MB
  unsigned short* w1t = (unsigned short*)ws; ws += (size_t)NN1 * DD * 2;         // 24 MB
  unsigned short* w2t = (unsigned short*)ws; ws += (size_t)DD * DD * 2;          //  8 MB
  unsigned short* Qb  = (unsigned short*)ws; ws += (size_t)BB * HH * SS * DHH * 2; // 16 MB
  unsigned short* Kb  = (unsigned short*)ws; ws += (size_t)BB * HH * SS * DHH * 2; // 16 MB
  unsigned short* Vt  = (unsigned short*)ws; ws += (size_t)BB * HH * SS * DHH * 2; // 16 MB
  unsigned short* Ob  = (unsigned short*)ws; ws += (size_t)MM * DD * 2;          // 16 MB

  k_cvt<<<dim3((MM * DD) / 1024), 256, 0, stream>>>(x, xb);
  k_transpose<<<dim3(NN1 / 32, DD / 32), dim3(32, 8), 0, stream>>>(Wqkv, w1t, DD, NN1);
  k_transpose<<<dim3(DD / 32, DD / 32), dim3(32, 8), 0, stream>>>(Wproj, w2t, DD, DD);
  k_gemm1<<<dim3(NN1 / 128, MM / 128), 256, 0, stream>>>(xb, w1t, bqkv, Qb, Kb, Vt);
  k_attn<<<dim3(SS / 64, BB * HH), 256, 0, stream>>>(Qb, Kb, Vt, Ob);
  k_gemm2<<<dim3(DD / 128, MM / 128), 256, 0, stream>>>(Ob, w2t, bproj, out);
}

// Round 2
// 355.528 us; speedup vs baseline: 1.4567x; 1.4567x over previous
//
#include <hip/hip_runtime.h>
#include <hip/hip_bf16.h>

#define BB 2
#define SS 2048
#define DD 2048
#define HH 16
#define DHH 128
#define MM 4096      // B*S
#define NN1 6144     // 3*D

typedef __attribute__((ext_vector_type(8))) short bf16x8;
typedef __attribute__((ext_vector_type(4))) float f32x4;
typedef unsigned int u32;

static __device__ __forceinline__ unsigned short f2bf(float f) {
  union { float f; u32 u; } v; v.f = f;
  return (unsigned short)((v.u + 0x7FFFu + ((v.u >> 16) & 1u)) >> 16);
}

static __device__ __forceinline__ void gload_lds16(const void* g, void* l) {
  __builtin_amdgcn_global_load_lds((const __attribute__((address_space(1))) u32*)g,
                                   (__attribute__((address_space(3))) u32*)l, 16, 0, 0);
}

// f32 -> bf16 elementwise, 4 elems/thread
__global__ __launch_bounds__(256) void k_cvt(const float* __restrict__ in,
                                             unsigned short* __restrict__ out) {
  int i = blockIdx.x * 256 + threadIdx.x;
  float4 v = ((const float4*)in)[i];
  ushort4 o;
  o.x = f2bf(v.x); o.y = f2bf(v.y); o.z = f2bf(v.z); o.w = f2bf(v.w);
  ((ushort4*)out)[i] = o;
}

// transpose f32 [R][C] -> bf16 [C][R]
__global__ __launch_bounds__(256) void k_transpose(const float* __restrict__ in,
                                                   unsigned short* __restrict__ out,
                                                   int R, int C) {
  __shared__ float t[32][33];
  int bx = blockIdx.x * 32, by = blockIdx.y * 32;
  int tx = threadIdx.x, ty = threadIdx.y;
  #pragma unroll
  for (int i = ty; i < 32; i += 8)
    t[i][tx] = in[(size_t)(by + i) * C + bx + tx];
  __syncthreads();
  #pragma unroll
  for (int i = ty; i < 32; i += 8)
    out[(size_t)(bx + i) * R + by + tx] = f2bf(t[tx][i]);
}

// ---- GEMM1: C = x(bf16)[M][K] * Wqkv^T(bf16)[N][K] + bqkv, scatter to Q/K/Vt ----
__global__ __launch_bounds__(256) void k_gemm1(const unsigned short* __restrict__ A,
                                               const unsigned short* __restrict__ Bt,
                                               const float* __restrict__ bias,
                                               unsigned short* __restrict__ Qb,
                                               unsigned short* __restrict__ Kb,
                                               unsigned short* __restrict__ Vt) {
  __shared__ __align__(16) unsigned short At[128 * 32];
  __shared__ __align__(16) unsigned short Bs[128 * 32];
  const int tid = threadIdx.x;
  const int wave = tid >> 6, lane = tid & 63;
  const int m0 = blockIdx.y * 128, n0 = blockIdx.x * 128;
  const int wr = wave >> 1, wc = wave & 1;
  const int lrow = lane & 15, lk = (lane >> 4) << 3;
  f32x4 acc[4][4] = {};
  for (int k0 = 0; k0 < DD; k0 += 32) {
    __syncthreads();
    #pragma unroll
    for (int r = 0; r < 2; ++r) {
      int f = r * 256 + tid;
      int row = f >> 2, col = (f & 3) << 3;
      gload_lds16(A + (size_t)(m0 + row) * DD + k0 + col, (char*)At + r * 4096 + wave * 1024);
      gload_lds16(Bt + (size_t)(n0 + row) * DD + k0 + col, (char*)Bs + r * 4096 + wave * 1024);
    }
    __syncthreads();
    bf16x8 af[4], bfv[4];
    #pragma unroll
    for (int i = 0; i < 4; ++i)
      af[i] = *(const bf16x8*)(At + (wr * 64 + i * 16 + lrow) * 32 + lk);
    #pragma unroll
    for (int j = 0; j < 4; ++j)
      bfv[j] = *(const bf16x8*)(Bs + (wc * 64 + j * 16 + lrow) * 32 + lk);
    #pragma unroll
    for (int i = 0; i < 4; ++i)
      #pragma unroll
      for (int j = 0; j < 4; ++j)
        acc[i][j] = __builtin_amdgcn_mfma_f32_16x16x32_bf16(af[i], bfv[j], acc[i][j], 0, 0, 0);
  }
  const int head = (n0 >> 7) & 15, which = n0 >> 11;
  #pragma unroll
  for (int i = 0; i < 4; ++i) {
    int rowb = m0 + wr * 64 + i * 16 + ((lane >> 4) << 2);
    int bb = rowb >> 11, s = rowb & 2047;
    #pragma unroll
    for (int j = 0; j < 4; ++j) {
      int gcol = n0 + wc * 64 + j * 16 + (lane & 15);
      int dh = gcol & 127;
      float bv = bias[gcol];
      if (which == 2) {
        ushort4 p;
        p.x = f2bf(acc[i][j][0] + bv);
        p.y = f2bf(acc[i][j][1] + bv);
        p.z = f2bf(acc[i][j][2] + bv);
        p.w = f2bf(acc[i][j][3] + bv);
        *(ushort4*)(Vt + ((size_t)(bb * HH + head) * DHH + dh) * SS + s) = p;
      } else {
        unsigned short* dst = (which == 0 ? Qb : Kb) + ((size_t)(bb * HH + head) * SS + s) * DHH + dh;
        dst[0]       = f2bf(acc[i][j][0] + bv);
        dst[DHH]     = f2bf(acc[i][j][1] + bv);
        dst[2 * DHH] = f2bf(acc[i][j][2] + bv);
        dst[3 * DHH] = f2bf(acc[i][j][3] + bv);
      }
    }
  }
}

// ---- flash attention v2: 128 q rows/block (4 waves x 32), KVBLK=64, swizzled LDS,
//      double-buffered staging, heavy-blocks-first ----
__global__ __launch_bounds__(256, 2) void k_attn(const unsigned short* __restrict__ Qb,
                                                 const unsigned short* __restrict__ Kb,
                                                 const unsigned short* __restrict__ Vt,
                                                 unsigned short* __restrict__ O) {
  __shared__ __align__(16) unsigned short Kt[2][64 * 128];   // [kv][dh], XOR-swizzled
  __shared__ __align__(16) unsigned short Vs[2][128 * 64];   // [dh][kv], XOR-swizzled
  __shared__ __align__(16) unsigned short Pl[4][32 * 64];    // per-wave P, swizzled
  const int qtl = gridDim.x - 1 - blockIdx.x;   // heavy blocks dispatch first
  const int bh = blockIdx.y;
  const int b = bh >> 4, h = bh & 15;
  const int tid = threadIdx.x, wave = tid >> 6, lane = tid & 63;
  const int g = lane >> 4, c = lane & 15;
  const int qbase = qtl * 128, q0w = qbase + wave * 32;
  const unsigned short* Qp = Qb + (size_t)bh * SS * DHH;
  const unsigned short* Kp = Kb + (size_t)bh * SS * DHH;
  const unsigned short* Vp = Vt + (size_t)bh * DHH * SS;

  // Q fragments hoisted: 2 m-frags x 4 k-chunks
  bf16x8 qf[2][4];
  #pragma unroll
  for (int m = 0; m < 2; ++m)
    #pragma unroll
    for (int ks = 0; ks < 4; ++ks)
      qf[m][ks] = *(const bf16x8*)(Qp + (size_t)(q0w + m * 16 + c) * DHH + ks * 32 + g * 8);

  f32x4 acc[2][8] = {};
  float mrow[2][4], lsum[2][4];
  #pragma unroll
  for (int m = 0; m < 2; ++m)
    #pragma unroll
    for (int r = 0; r < 4; ++r) { mrow[m][r] = -1e30f; lsum[m][r] = 0.f; }
  const float scale = 0.08838834764831845f;  // 1/sqrt(128)

  // stage: linear LDS dest + inverse-swizzled global source (rule 21)
  auto stage = [&](int buf, int kv0) {
    #pragma unroll
    for (int r = 0; r < 4; ++r) {
      int base = r * 4096 + wave * 1024;
      int off = base + (lane << 4);
      { int row = off >> 8; int cb = (off & 255) ^ ((row & 7) << 4);
        gload_lds16((const char*)Kp + (size_t)(kv0 + row) * 256 + cb,
                    (char*)Kt[buf] + base); }
      { int row = off >> 7; int cb = (off & 127) ^ ((row & 7) << 4);
        gload_lds16((const char*)Vp + (size_t)row * (SS * 2) + (size_t)kv0 * 2 + cb,
                    (char*)Vs[buf] + base); }
    }
  };

  const int ntiles = 2 * qtl + 2;
  stage(0, 0);
  __syncthreads();

  for (int t = 0; t < ntiles; ++t) {
    const int cur = t & 1;
    const int kv0 = t * 64;
    if (t + 1 < ntiles) stage(cur ^ 1, kv0 + 64);   // overlap with compute
    if (kv0 <= q0w + 31) {                          // wave-uniform causal skip
      const unsigned short* K_ = Kt[cur];
      const unsigned short* V_ = Vs[cur];
      // QK^T
      f32x4 sa[2][4] = {};
      __builtin_amdgcn_s_setprio(1);
      #pragma unroll
      for (int nb = 0; nb < 4; ++nb) {
        const int rk = nb * 16 + c;
        const int swz = (rk & 7) << 4;
        #pragma unroll
        for (int ks = 0; ks < 4; ++ks) {
          bf16x8 kf = *(const bf16x8*)((const char*)K_ + rk * 256 + ((ks * 64 + g * 16) ^ swz));
          sa[0][nb] = __builtin_amdgcn_mfma_f32_16x16x32_bf16(qf[0][ks], kf, sa[0][nb], 0, 0, 0);
          sa[1][nb] = __builtin_amdgcn_mfma_f32_16x16x32_bf16(qf[1][ks], kf, sa[1][nb], 0, 0, 0);
        }
      }
      __builtin_amdgcn_s_setprio(0);
      // online softmax per m-frag
      #pragma unroll
      for (int m = 0; m < 2; ++m) {
        const int rq = q0w + m * 16 + g * 4;
        float p[4][4], tm[4], rs[4], sf[4];
        #pragma unroll
        for (int r = 0; r < 4; ++r) tm[r] = -1e30f;
        #pragma unroll
        for (int nb = 0; nb < 4; ++nb)
          #pragma unroll
          for (int r = 0; r < 4; ++r) {
            float s = sa[m][nb][r] * scale;
            if (kv0 + nb * 16 + c > rq + r) s = -1e30f;
            p[nb][r] = s;
            tm[r] = fmaxf(tm[r], s);
          }
        #pragma unroll
        for (int off = 1; off < 16; off <<= 1)
          #pragma unroll
          for (int r = 0; r < 4; ++r)
            tm[r] = fmaxf(tm[r], __shfl_xor(tm[r], off, 64));
        #pragma unroll
        for (int r = 0; r < 4; ++r) {
          float mnew = fmaxf(mrow[m][r], tm[r]);
          sf[r] = __expf(mrow[m][r] - mnew);
          mrow[m][r] = mnew;
          rs[r] = 0.f;
          #pragma unroll
          for (int nb = 0; nb < 4; ++nb) {
            p[nb][r] = __expf(p[nb][r] - mnew);
            rs[r] += p[nb][r];
          }
        }
        #pragma unroll
        for (int off = 1; off < 16; off <<= 1)
          #pragma unroll
          for (int r = 0; r < 4; ++r)
            rs[r] += __shfl_xor(rs[r], off, 64);
        #pragma unroll
        for (int r = 0; r < 4; ++r) lsum[m][r] = lsum[m][r] * sf[r] + rs[r];
        #pragma unroll
        for (int nf = 0; nf < 8; ++nf)
          #pragma unroll
          for (int r = 0; r < 4; ++r) acc[m][nf][r] *= sf[r];
        // P (C/D layout) -> swizzled per-wave LDS
        #pragma unroll
        for (int nb = 0; nb < 4; ++nb)
          #pragma unroll
          for (int r = 0; r < 4; ++r) {
            int rowp = m * 16 + g * 4 + r;
            int cbyte = ((nb * 16 + c) * 2) ^ ((rowp & 7) << 4);
            *(unsigned short*)((char*)Pl[wave] + rowp * 128 + cbyte) = f2bf(p[nb][r]);
          }
      }
      asm volatile("s_waitcnt lgkmcnt(0)" ::: "memory");
      __builtin_amdgcn_sched_barrier(0);
      // P fragments (A-layout) from swizzled LDS
      bf16x8 pf[2][2];
      #pragma unroll
      for (int m = 0; m < 2; ++m)
        #pragma unroll
        for (int c2 = 0; c2 < 2; ++c2) {
          int rowp = m * 16 + c;
          pf[m][c2] = *(const bf16x8*)((const char*)Pl[wave] + rowp * 128 +
                                       ((c2 * 64 + g * 16) ^ ((rowp & 7) << 4)));
        }
      // PV
      __builtin_amdgcn_s_setprio(1);
      #pragma unroll
      for (int nf = 0; nf < 8; ++nf) {
        const int rv = nf * 16 + c;
        const int swzv = (rv & 7) << 4;
        #pragma unroll
        for (int c2 = 0; c2 < 2; ++c2) {
          bf16x8 vf = *(const bf16x8*)((const char*)V_ + rv * 128 + ((c2 * 64 + g * 16) ^ swzv));
          acc[0][nf] = __builtin_amdgcn_mfma_f32_16x16x32_bf16(pf[0][c2], vf, acc[0][nf], 0, 0, 0);
          acc[1][nf] = __builtin_amdgcn_mfma_f32_16x16x32_bf16(pf[1][c2], vf, acc[1][nf], 0, 0, 0);
        }
      }
      __builtin_amdgcn_s_setprio(0);
    }
    __syncthreads();
  }

  unsigned short* Op = O + (size_t)b * SS * DD + (size_t)h * DHH;
  #pragma unroll
  for (int m = 0; m < 2; ++m) {
    float inv[4];
    #pragma unroll
    for (int r = 0; r < 4; ++r) inv[r] = 1.0f / lsum[m][r];
    #pragma unroll
    for (int nf = 0; nf < 8; ++nf)
      #pragma unroll
      for (int r = 0; r < 4; ++r) {
        int q = q0w + m * 16 + g * 4 + r;
        Op[(size_t)q * DD + nf * 16 + c] = f2bf(acc[m][nf][r] * inv[r]);
      }
  }
}

// ---- GEMM2: out = O(bf16)[M][D] * Wproj^T(bf16)[D][D] + bproj, f32 out ----
__global__ __launch_bounds__(256) void k_gemm2(const unsigned short* __restrict__ A,
                                               const unsigned short* __restrict__ Bt,
                                               const float* __restrict__ bias,
                                               float* __restrict__ out) {
  __shared__ __align__(16) unsigned short At[128 * 32];
  __shared__ __align__(16) unsigned short Bs[128 * 32];
  const int tid = threadIdx.x;
  const int wave = tid >> 6, lane = tid & 63;
  const int m0 = blockIdx.y * 128, n0 = blockIdx.x * 128;
  const int wr = wave >> 1, wc = wave & 1;
  const int lrow = lane & 15, lk = (lane >> 4) << 3;
  f32x4 acc[4][4] = {};
  for (int k0 = 0; k0 < DD; k0 += 32) {
    __syncthreads();
    #pragma unroll
    for (int r = 0; r < 2; ++r) {
      int f = r * 256 + tid;
      int row = f >> 2, col = (f & 3) << 3;
      gload_lds16(A + (size_t)(m0 + row) * DD + k0 + col, (char*)At + r * 4096 + wave * 1024);
      gload_lds16(Bt + (size_t)(n0 + row) * DD + k0 + col, (char*)Bs + r * 4096 + wave * 1024);
    }
    __syncthreads();
    bf16x8 af[4], bfv[4];
    #pragma unroll
    for (int i = 0; i < 4; ++i)
      af[i] = *(const bf16x8*)(At + (wr * 64 + i * 16 + lrow) * 32 + lk);
    #pragma unroll
    for (int j = 0; j < 4; ++j)
      bfv[j] = *(const bf16x8*)(Bs + (wc * 64 + j * 16 + lrow) * 32 + lk);
    #pragma unroll
    for (int i = 0; i < 4; ++i)
      #pragma unroll
      for (int j = 0; j < 4; ++j)
        acc[i][j] = __builtin_amdgcn_mfma_f32_16x16x32_bf16(af[i], bfv[j], acc[i][j], 0, 0, 0);
  }
  #pragma unroll
  for (int i = 0; i < 4; ++i) {
    int rowb = m0 + wr * 64 + i * 16 + ((lane >> 4) << 2);
    #pragma unroll
    for (int j = 0; j < 4; ++j) {
      int gcol = n0 + wc * 64 + j * 16 + (lane & 15);
      float bv = bias[gcol];
      #pragma unroll
      for (int rg = 0; rg < 4; ++rg)
        out[(size_t)(rowb + rg) * DD + gcol] = acc[i][j][rg] + bv;
    }
  }
}

extern "C" void kernel_launch(void* const* d_in, const int* in_sizes, int n_in,
                              void* d_out, int out_size, void* d_ws, size_t ws_size,
                              hipStream_t stream) {
  const float* x     = (const float*)d_in[0];
  const float* Wqkv  = (const float*)d_in[1];
  const float* bqkv  = (const float*)d_in[2];
  const float* Wproj = (const float*)d_in[3];
  const float* bproj = (const float*)d_in[4];
  float* out = (float*)d_out;

  char* ws = (char*)d_ws;
  unsigned short* xb  = (unsigned short*)ws; ws += (size_t)MM * DD * 2;
  unsigned short* w1t = (unsigned short*)ws; ws += (size_t)NN1 * DD * 2;
  unsigned short* w2t = (unsigned short*)ws; ws += (size_t)DD * DD * 2;
  unsigned short* Qb  = (unsigned short*)ws; ws += (size_t)BB * HH * SS * DHH * 2;
  unsigned short* Kb  = (unsigned short*)ws; ws += (size_t)BB * HH * SS * DHH * 2;
  unsigned short* Vt  = (unsigned short*)ws; ws += (size_t)BB * HH * SS * DHH * 2;
  unsigned short* Ob  = (unsigned short*)ws; ws += (size_t)MM * DD * 2;

  k_cvt<<<dim3((MM * DD) / 1024), 256, 0, stream>>>(x, xb);
  k_transpose<<<dim3(NN1 / 32, DD / 32), dim3(32, 8), 0, stream>>>(Wqkv, w1t, DD, NN1);
  k_transpose<<<dim3(DD / 32, DD / 32), dim3(32, 8), 0, stream>>>(Wproj, w2t, DD, DD);
  k_gemm1<<<dim3(NN1 / 128, MM / 128), 256, 0, stream>>>(xb, w1t, bqkv, Qb, Kb, Vt);
  k_attn<<<dim3(SS / 128, BB * HH), 256, 0, stream>>>(Qb, Kb, Vt, Ob);
  k_gemm2<<<dim3(DD / 128, MM / 128), 256, 0, stream>>>(Ob, w2t, bproj, out);
}

// Round 3
// 321.652 us; speedup vs baseline: 1.6101x; 1.1053x over previous
//
#include <hip/hip_runtime.h>
#include <hip/hip_bf16.h>

#define BB 2
#define SS 2048
#define DD 2048
#define HH 16
#define DHH 128
#define MM 4096      // B*S
#define NN1 6144     // 3*D
#define NTILES (DD / 64)   // 32 K-tiles of 64

typedef __attribute__((ext_vector_type(8))) short bf16x8;
typedef __attribute__((ext_vector_type(4))) float f32x4;
typedef unsigned int u32;

static __device__ __forceinline__ unsigned short f2bf(float f) {
  union { float f; u32 u; } v; v.f = f;
  return (unsigned short)((v.u + 0x7FFFu + ((v.u >> 16) & 1u)) >> 16);
}

static __device__ __forceinline__ void gload_lds16(const void* g, void* l) {
  __builtin_amdgcn_global_load_lds((const __attribute__((address_space(1))) u32*)g,
                                   (__attribute__((address_space(3))) u32*)l, 16, 0, 0);
}

// f32 -> bf16 elementwise, 4 elems/thread
__global__ __launch_bounds__(256) void k_cvt(const float* __restrict__ in,
                                             unsigned short* __restrict__ out) {
  int i = blockIdx.x * 256 + threadIdx.x;
  float4 v = ((const float4*)in)[i];
  ushort4 o;
  o.x = f2bf(v.x); o.y = f2bf(v.y); o.z = f2bf(v.z); o.w = f2bf(v.w);
  ((ushort4*)out)[i] = o;
}

// transpose f32 [R][C] -> bf16 [C][R]
__global__ __launch_bounds__(256) void k_transpose(const float* __restrict__ in,
                                                   unsigned short* __restrict__ out,
                                                   int R, int C) {
  __shared__ float t[32][33];
  int bx = blockIdx.x * 32, by = blockIdx.y * 32;
  int tx = threadIdx.x, ty = threadIdx.y;
  #pragma unroll
  for (int i = ty; i < 32; i += 8)
    t[i][tx] = in[(size_t)(by + i) * C + bx + tx];
  __syncthreads();
  #pragma unroll
  for (int i = ty; i < 32; i += 8)
    out[(size_t)(bx + i) * R + by + tx] = f2bf(t[tx][i]);
}

// ================= 256x128 triple-buffered counted-vmcnt GEMM core =================
// A: [256 rows][K] bf16 (row stride 4096B), B: [128 rows][K] bf16. K = 2048.
// 512 threads = 8 waves as 4M x 2N; per-wave 64x64 output (acc[4][4]).
// LDS: A 3 x 32KB + B 3 x 16KB = 144KB, XOR-swizzled (cb ^= (row&7)<<4).
__device__ __forceinline__ void gemm_core(const char* __restrict__ Ag,
                                          const char* __restrict__ Bg,
                                          char* Alds, char* Blds,
                                          f32x4 acc[4][4]) {
  const int tid = threadIdx.x;
  const int wave = tid >> 6, lane = tid & 63;
  const int g = lane >> 4, c = lane & 15;
  const int wm = wave >> 1, wn = wave & 1;

  // stage: linear LDS dest (wave-uniform base + lane*16), inverse-swizzled global src
  auto stageA = [&](int buf, int kt) {
    #pragma unroll
    for (int q = 0; q < 4; ++q) {
      int off = q * 8192 + wave * 1024 + (lane << 4);
      int row = off >> 7, cb = off & 127;
      gload_lds16(Ag + (size_t)row * 4096 + kt * 128 + (cb ^ ((row & 7) << 4)),
                  Alds + buf * 32768 + q * 8192 + wave * 1024);
    }
  };
  auto stageB = [&](int buf, int kt) {
    #pragma unroll
    for (int q = 0; q < 2; ++q) {
      int off = q * 8192 + wave * 1024 + (lane << 4);
      int row = off >> 7, cb = off & 127;
      gload_lds16(Bg + (size_t)row * 4096 + kt * 128 + (cb ^ ((row & 7) << 4)),
                  Blds + buf * 16384 + q * 8192 + wave * 1024);
    }
  };

  // prologue: tiles 0 and 1 staged; wait for tile 0 (oldest 6), tile 1 in flight
  stageA(0, 0); stageB(0, 0);
  stageA(1, 1); stageB(1, 1);
  asm volatile("s_waitcnt vmcnt(6)" ::: "memory");
  __builtin_amdgcn_sched_barrier(0);
  __builtin_amdgcn_s_barrier();

  for (int t = 0; t < NTILES; ++t) {
    const int buf = t % 3;
    const char* Ab = Alds + buf * 32768;
    const char* Bb = Blds + buf * 16384;
    // ---- phase 1: A frags (8) + B half0 (4); stage A(t+2); 16 MFMA ----
    bf16x8 af[4][2], b0[2][2];
    #pragma unroll
    for (int i = 0; i < 4; ++i) {
      int row = wm * 64 + i * 16 + c;
      #pragma unroll
      for (int kk = 0; kk < 2; ++kk)
        af[i][kk] = *(const bf16x8*)(Ab + row * 128 + ((kk * 64 + g * 16) ^ ((row & 7) << 4)));
    }
    #pragma unroll
    for (int j = 0; j < 2; ++j) {
      int row = wn * 64 + j * 16 + c;
      #pragma unroll
      for (int kk = 0; kk < 2; ++kk)
        b0[j][kk] = *(const bf16x8*)(Bb + row * 128 + ((kk * 64 + g * 16) ^ ((row & 7) << 4)));
    }
    if (t + 2 < NTILES) stageA((t + 2) % 3, t + 2);
    __builtin_amdgcn_s_barrier();
    asm volatile("s_waitcnt lgkmcnt(0)" ::: "memory");
    __builtin_amdgcn_sched_barrier(0);
    __builtin_amdgcn_s_setprio(1);
    #pragma unroll
    for (int i = 0; i < 4; ++i)
      #pragma unroll
      for (int j = 0; j < 2; ++j)
        #pragma unroll
        for (int kk = 0; kk < 2; ++kk)
          acc[i][j] = __builtin_amdgcn_mfma_f32_16x16x32_bf16(af[i][kk], b0[j][kk], acc[i][j], 0, 0, 0);
    __builtin_amdgcn_s_setprio(0);
    __builtin_amdgcn_s_barrier();
    // ---- phase 2: B half1 (4); stage B(t+2); 16 MFMA; counted vmcnt ----
    bf16x8 b1[2][2];
    #pragma unroll
    for (int j = 0; j < 2; ++j) {
      int row = wn * 64 + (2 + j) * 16 + c;
      #pragma unroll
      for (int kk = 0; kk < 2; ++kk)
        b1[j][kk] = *(const bf16x8*)(Bb + row * 128 + ((kk * 64 + g * 16) ^ ((row & 7) << 4)));
    }
    if (t + 2 < NTILES) stageB((t + 2) % 3, t + 2);
    __builtin_amdgcn_s_barrier();
    asm volatile("s_waitcnt lgkmcnt(0)" ::: "memory");
    __builtin_amdgcn_sched_barrier(0);
    __builtin_amdgcn_s_setprio(1);
    #pragma unroll
    for (int i = 0; i < 4; ++i)
      #pragma unroll
      for (int j = 0; j < 2; ++j)
        #pragma unroll
        for (int kk = 0; kk < 2; ++kk)
          acc[i][j + 2] = __builtin_amdgcn_mfma_f32_16x16x32_bf16(af[i][kk], b1[j][kk], acc[i][j + 2], 0, 0, 0);
    __builtin_amdgcn_s_setprio(0);
    if (t < NTILES - 1) {
      // next tile's staging (issued 2 tiles back) must be complete in ALL waves:
      // own counted wait + barrier. t+2's 6 loads (just issued) are the newest.
      if (t + 2 < NTILES) { asm volatile("s_waitcnt vmcnt(6)" ::: "memory"); }
      else                { asm volatile("s_waitcnt vmcnt(0)" ::: "memory"); }
      __builtin_amdgcn_sched_barrier(0);
      __builtin_amdgcn_s_barrier();
    }
  }
}

// ---- GEMM1: x[M][K] * Wqkv^T[N][K] + bqkv -> scatter Q/K/Vt ----
__global__ __launch_bounds__(512, 1) void k_gemm1(const unsigned short* __restrict__ A,
                                                  const unsigned short* __restrict__ Bt,
                                                  const float* __restrict__ bias,
                                                  unsigned short* __restrict__ Qb,
                                                  unsigned short* __restrict__ Kb,
                                                  unsigned short* __restrict__ Vt) {
  __shared__ __align__(16) char lds[147456];
  const int n0 = blockIdx.x * 128, m0 = blockIdx.y * 256;
  f32x4 acc[4][4] = {};
  gemm_core((const char*)A + (size_t)m0 * 4096,
            (const char*)Bt + (size_t)n0 * 4096,
            lds, lds + 98304, acc);
  const int lane = threadIdx.x & 63, wave = threadIdx.x >> 6;
  const int g = lane >> 4, c = lane & 15;
  const int wm = wave >> 1, wn = wave & 1;
  const int head = (n0 >> 7) & 15, which = n0 >> 11;
  #pragma unroll
  for (int i = 0; i < 4; ++i) {
    int rowb = m0 + wm * 64 + i * 16 + g * 4;
    int bb = rowb >> 11, s = rowb & 2047;
    #pragma unroll
    for (int j = 0; j < 4; ++j) {
      int dh = wn * 64 + j * 16 + c;
      float bv = bias[n0 + dh];
      if (which == 2) {
        ushort4 p;
        p.x = f2bf(acc[i][j][0] + bv);
        p.y = f2bf(acc[i][j][1] + bv);
        p.z = f2bf(acc[i][j][2] + bv);
        p.w = f2bf(acc[i][j][3] + bv);
        *(ushort4*)(Vt + ((size_t)(bb * HH + head) * DHH + dh) * SS + s) = p;
      } else {
        unsigned short* dst = (which == 0 ? Qb : Kb) + ((size_t)(bb * HH + head) * SS + s) * DHH + dh;
        dst[0]       = f2bf(acc[i][j][0] + bv);
        dst[DHH]     = f2bf(acc[i][j][1] + bv);
        dst[2 * DHH] = f2bf(acc[i][j][2] + bv);
        dst[3 * DHH] = f2bf(acc[i][j][3] + bv);
      }
    }
  }
}

// ---- GEMM2: O[M][D] * Wproj^T[D][D] + bproj -> f32 out ----
__global__ __launch_bounds__(512, 1) void k_gemm2(const unsigned short* __restrict__ A,
                                                  const unsigned short* __restrict__ Bt,
                                                  const float* __restrict__ bias,
                                                  float* __restrict__ out) {
  __shared__ __align__(16) char lds[147456];
  const int n0 = blockIdx.x * 128, m0 = blockIdx.y * 256;
  f32x4 acc[4][4] = {};
  gemm_core((const char*)A + (size_t)m0 * 4096,
            (const char*)Bt + (size_t)n0 * 4096,
            lds, lds + 98304, acc);
  const int lane = threadIdx.x & 63, wave = threadIdx.x >> 6;
  const int g = lane >> 4, c = lane & 15;
  const int wm = wave >> 1, wn = wave & 1;
  #pragma unroll
  for (int i = 0; i < 4; ++i) {
    int rowb = m0 + wm * 64 + i * 16 + g * 4;
    #pragma unroll
    for (int j = 0; j < 4; ++j) {
      int gcol = n0 + wn * 64 + j * 16 + c;
      float bv = bias[gcol];
      #pragma unroll
      for (int r = 0; r < 4; ++r)
        out[(size_t)(rowb + r) * DD + gcol] = acc[i][j][r] + bv;
    }
  }
}

// ---- flash attention: 128 q rows/block (4 waves x 32), KVBLK=64, swizzled LDS,
//      double-buffered staging, heavy-blocks-first ----
__global__ __launch_bounds__(256, 2) void k_attn(const unsigned short* __restrict__ Qb,
                                                 const unsigned short* __restrict__ Kb,
                                                 const unsigned short* __restrict__ Vt,
                                                 unsigned short* __restrict__ O) {
  __shared__ __align__(16) unsigned short Kt[2][64 * 128];
  __shared__ __align__(16) unsigned short Vs[2][128 * 64];
  __shared__ __align__(16) unsigned short Pl[4][32 * 64];
  const int qtl = gridDim.x - 1 - blockIdx.x;
  const int bh = blockIdx.y;
  const int b = bh >> 4, h = bh & 15;
  const int tid = threadIdx.x, wave = tid >> 6, lane = tid & 63;
  const int g = lane >> 4, c = lane & 15;
  const int qbase = qtl * 128, q0w = qbase + wave * 32;
  const unsigned short* Qp = Qb + (size_t)bh * SS * DHH;
  const unsigned short* Kp = Kb + (size_t)bh * SS * DHH;
  const unsigned short* Vp = Vt + (size_t)bh * DHH * SS;

  bf16x8 qf[2][4];
  #pragma unroll
  for (int m = 0; m < 2; ++m)
    #pragma unroll
    for (int ks = 0; ks < 4; ++ks)
      qf[m][ks] = *(const bf16x8*)(Qp + (size_t)(q0w + m * 16 + c) * DHH + ks * 32 + g * 8);

  f32x4 acc[2][8] = {};
  float mrow[2][4], lsum[2][4];
  #pragma unroll
  for (int m = 0; m < 2; ++m)
    #pragma unroll
    for (int r = 0; r < 4; ++r) { mrow[m][r] = -1e30f; lsum[m][r] = 0.f; }
  const float scale = 0.08838834764831845f;

  auto stage = [&](int buf, int kv0) {
    #pragma unroll
    for (int r = 0; r < 4; ++r) {
      int base = r * 4096 + wave * 1024;
      int off = base + (lane << 4);
      { int row = off >> 8; int cb = (off & 255) ^ ((row & 7) << 4);
        gload_lds16((const char*)Kp + (size_t)(kv0 + row) * 256 + cb,
                    (char*)Kt[buf] + base); }
      { int row = off >> 7; int cb = (off & 127) ^ ((row & 7) << 4);
        gload_lds16((const char*)Vp + (size_t)row * (SS * 2) + (size_t)kv0 * 2 + cb,
                    (char*)Vs[buf] + base); }
    }
  };

  const int ntiles = 2 * qtl + 2;
  stage(0, 0);
  __syncthreads();

  for (int t = 0; t < ntiles; ++t) {
    const int cur = t & 1;
    const int kv0 = t * 64;
    if (t + 1 < ntiles) stage(cur ^ 1, kv0 + 64);
    if (kv0 <= q0w + 31) {
      const unsigned short* K_ = Kt[cur];
      const unsigned short* V_ = Vs[cur];
      f32x4 sa[2][4] = {};
      __builtin_amdgcn_s_setprio(1);
      #pragma unroll
      for (int nb = 0; nb < 4; ++nb) {
        const int rk = nb * 16 + c;
        const int swz = (rk & 7) << 4;
        #pragma unroll
        for (int ks = 0; ks < 4; ++ks) {
          bf16x8 kf = *(const bf16x8*)((const char*)K_ + rk * 256 + ((ks * 64 + g * 16) ^ swz));
          sa[0][nb] = __builtin_amdgcn_mfma_f32_16x16x32_bf16(qf[0][ks], kf, sa[0][nb], 0, 0, 0);
          sa[1][nb] = __builtin_amdgcn_mfma_f32_16x16x32_bf16(qf[1][ks], kf, sa[1][nb], 0, 0, 0);
        }
      }
      __builtin_amdgcn_s_setprio(0);
      #pragma unroll
      for (int m = 0; m < 2; ++m) {
        const int rq = q0w + m * 16 + g * 4;
        float p[4][4], tm[4], rs[4], sf[4];
        #pragma unroll
        for (int r = 0; r < 4; ++r) tm[r] = -1e30f;
        #pragma unroll
        for (int nb = 0; nb < 4; ++nb)
          #pragma unroll
          for (int r = 0; r < 4; ++r) {
            float s = sa[m][nb][r] * scale;
            if (kv0 + nb * 16 + c > rq + r) s = -1e30f;
            p[nb][r] = s;
            tm[r] = fmaxf(tm[r], s);
          }
        #pragma unroll
        for (int off = 1; off < 16; off <<= 1)
          #pragma unroll
          for (int r = 0; r < 4; ++r)
            tm[r] = fmaxf(tm[r], __shfl_xor(tm[r], off, 64));
        #pragma unroll
        for (int r = 0; r < 4; ++r) {
          float mnew = fmaxf(mrow[m][r], tm[r]);
          sf[r] = __expf(mrow[m][r] - mnew);
          mrow[m][r] = mnew;
          rs[r] = 0.f;
          #pragma unroll
          for (int nb = 0; nb < 4; ++nb) {
            p[nb][r] = __expf(p[nb][r] - mnew);
            rs[r] += p[nb][r];
          }
        }
        #pragma unroll
        for (int off = 1; off < 16; off <<= 1)
          #pragma unroll
          for (int r = 0; r < 4; ++r)
            rs[r] += __shfl_xor(rs[r], off, 64);
        #pragma unroll
        for (int r = 0; r < 4; ++r) lsum[m][r] = lsum[m][r] * sf[r] + rs[r];
        #pragma unroll
        for (int nf = 0; nf < 8; ++nf)
          #pragma unroll
          for (int r = 0; r < 4; ++r) acc[m][nf][r] *= sf[r];
        #pragma unroll
        for (int nb = 0; nb < 4; ++nb)
          #pragma unroll
          for (int r = 0; r < 4; ++r) {
            int rowp = m * 16 + g * 4 + r;
            int cbyte = ((nb * 16 + c) * 2) ^ ((rowp & 7) << 4);
            *(unsigned short*)((char*)Pl[wave] + rowp * 128 + cbyte) = f2bf(p[nb][r]);
          }
      }
      asm volatile("s_waitcnt lgkmcnt(0)" ::: "memory");
      __builtin_amdgcn_sched_barrier(0);
      bf16x8 pf[2][2];
      #pragma unroll
      for (int m = 0; m < 2; ++m)
        #pragma unroll
        for (int c2 = 0; c2 < 2; ++c2) {
          int rowp = m * 16 + c;
          pf[m][c2] = *(const bf16x8*)((const char*)Pl[wave] + rowp * 128 +
                                       ((c2 * 64 + g * 16) ^ ((rowp & 7) << 4)));
        }
      __builtin_amdgcn_s_setprio(1);
      #pragma unroll
      for (int nf = 0; nf < 8; ++nf) {
        const int rv = nf * 16 + c;
        const int swzv = (rv & 7) << 4;
        #pragma unroll
        for (int c2 = 0; c2 < 2; ++c2) {
          bf16x8 vf = *(const bf16x8*)((const char*)V_ + rv * 128 + ((c2 * 64 + g * 16) ^ swzv));
          acc[0][nf] = __builtin_amdgcn_mfma_f32_16x16x32_bf16(pf[0][c2], vf, acc[0][nf], 0, 0, 0);
          acc[1][nf] = __builtin_amdgcn_mfma_f32_16x16x32_bf16(pf[1][c2], vf, acc[1][nf], 0, 0, 0);
        }
      }
      __builtin_amdgcn_s_setprio(0);
    }
    __syncthreads();
  }

  unsigned short* Op = O + (size_t)b * SS * DD + (size_t)h * DHH;
  #pragma unroll
  for (int m = 0; m < 2; ++m) {
    float inv[4];
    #pragma unroll
    for (int r = 0; r < 4; ++r) inv[r] = 1.0f / lsum[m][r];
    #pragma unroll
    for (int nf = 0; nf < 8; ++nf)
      #pragma unroll
      for (int r = 0; r < 4; ++r) {
        int q = q0w + m * 16 + g * 4 + r;
        Op[(size_t)q * DD + nf * 16 + c] = f2bf(acc[m][nf][r] * inv[r]);
      }
  }
}

extern "C" void kernel_launch(void* const* d_in, const int* in_sizes, int n_in,
                              void* d_out, int out_size, void* d_ws, size_t ws_size,
                              hipStream_t stream) {
  const float* x     = (const float*)d_in[0];
  const float* Wqkv  = (const float*)d_in[1];
  const float* bqkv  = (const float*)d_in[2];
  const float* Wproj = (const float*)d_in[3];
  const float* bproj = (const float*)d_in[4];
  float* out = (float*)d_out;

  char* ws = (char*)d_ws;
  unsigned short* xb  = (unsigned short*)ws; ws += (size_t)MM * DD * 2;
  unsigned short* w1t = (unsigned short*)ws; ws += (size_t)NN1 * DD * 2;
  unsigned short* w2t = (unsigned short*)ws; ws += (size_t)DD * DD * 2;
  unsigned short* Qb  = (unsigned short*)ws; ws += (size_t)BB * HH * SS * DHH * 2;
  unsigned short* Kb  = (unsigned short*)ws; ws += (size_t)BB * HH * SS * DHH * 2;
  unsigned short* Vt  = (unsigned short*)ws; ws += (size_t)BB * HH * SS * DHH * 2;
  unsigned short* Ob  = (unsigned short*)ws; ws += (size_t)MM * DD * 2;

  k_cvt<<<dim3((MM * DD) / 1024), 256, 0, stream>>>(x, xb);
  k_transpose<<<dim3(NN1 / 32, DD / 32), dim3(32, 8), 0, stream>>>(Wqkv, w1t, DD, NN1);
  k_transpose<<<dim3(DD / 32, DD / 32), dim3(32, 8), 0, stream>>>(Wproj, w2t, DD, DD);
  k_gemm1<<<dim3(NN1 / 128, MM / 256), 512, 0, stream>>>(xb, w1t, bqkv, Qb, Kb, Vt);
  k_attn<<<dim3(SS / 128, BB * HH), 256, 0, stream>>>(Qb, Kb, Vt, Ob);
  k_gemm2<<<dim3(DD / 128, MM / 256), 512, 0, stream>>>(Ob, w2t, bproj, out);
}

// Round 5
// 268.829 us; speedup vs baseline: 1.9265x; 1.1965x over previous
//
#include <hip/hip_runtime.h>
#include <hip/hip_bf16.h>

#define BB 2
#define SS 2048
#define DD 2048
#define HH 16
#define DHH 128
#define MM 4096      // B*S
#define NN1 6144     // 3*D
#define NTILES (DD / 64)   // 32 K-tiles of 64

typedef __attribute__((ext_vector_type(8))) short bf16x8;
typedef __attribute__((ext_vector_type(4))) float f32x4;
typedef unsigned int u32;

static __device__ __forceinline__ float exp2_hw(float x) {
  return __builtin_amdgcn_exp2f(x);   // v_exp_f32
}

static __device__ __forceinline__ unsigned short f2bf(float f) {
  union { float f; u32 u; } v; v.f = f;
  return (unsigned short)((v.u + 0x7FFFu + ((v.u >> 16) & 1u)) >> 16);
}

static __device__ __forceinline__ void gload_lds16(const void* g, void* l) {
  __builtin_amdgcn_global_load_lds((const __attribute__((address_space(1))) u32*)g,
                                   (__attribute__((address_space(3))) u32*)l, 16, 0, 0);
}

// f32 -> bf16 elementwise, 4 elems/thread
__global__ __launch_bounds__(256) void k_cvt(const float* __restrict__ in,
                                             unsigned short* __restrict__ out) {
  int i = blockIdx.x * 256 + threadIdx.x;
  float4 v = ((const float4*)in)[i];
  ushort4 o;
  o.x = f2bf(v.x); o.y = f2bf(v.y); o.z = f2bf(v.z); o.w = f2bf(v.w);
  ((ushort4*)out)[i] = o;
}

// transpose f32 [R][C] -> bf16 [C][R]
__global__ __launch_bounds__(256) void k_transpose(const float* __restrict__ in,
                                                   unsigned short* __restrict__ out,
                                                   int R, int C) {
  __shared__ float t[32][33];
  int bx = blockIdx.x * 32, by = blockIdx.y * 32;
  int tx = threadIdx.x, ty = threadIdx.y;
  #pragma unroll
  for (int i = ty; i < 32; i += 8)
    t[i][tx] = in[(size_t)(by + i) * C + bx + tx];
  __syncthreads();
  #pragma unroll
  for (int i = ty; i < 32; i += 8)
    out[(size_t)(bx + i) * R + by + tx] = f2bf(t[tx][i]);
}

// ================= 256x128 triple-buffered counted-vmcnt GEMM core =================
__device__ __forceinline__ void gemm_core(const char* __restrict__ Ag,
                                          const char* __restrict__ Bg,
                                          char* Alds, char* Blds,
                                          f32x4 acc[4][4]) {
  const int tid = threadIdx.x;
  const int wave = tid >> 6, lane = tid & 63;
  const int g = lane >> 4, c = lane & 15;
  const int wm = wave >> 1, wn = wave & 1;

  auto stageA = [&](int buf, int kt) {
    #pragma unroll
    for (int q = 0; q < 4; ++q) {
      int off = q * 8192 + wave * 1024 + (lane << 4);
      int row = off >> 7, cb = off & 127;
      gload_lds16(Ag + (size_t)row * 4096 + kt * 128 + (cb ^ ((row & 7) << 4)),
                  Alds + buf * 32768 + q * 8192 + wave * 1024);
    }
  };
  auto stageB = [&](int buf, int kt) {
    #pragma unroll
    for (int q = 0; q < 2; ++q) {
      int off = q * 8192 + wave * 1024 + (lane << 4);
      int row = off >> 7, cb = off & 127;
      gload_lds16(Bg + (size_t)row * 4096 + kt * 128 + (cb ^ ((row & 7) << 4)),
                  Blds + buf * 16384 + q * 8192 + wave * 1024);
    }
  };

  stageA(0, 0); stageB(0, 0);
  stageA(1, 1); stageB(1, 1);
  asm volatile("s_waitcnt vmcnt(6)" ::: "memory");
  __builtin_amdgcn_sched_barrier(0);
  __builtin_amdgcn_s_barrier();

  for (int t = 0; t < NTILES; ++t) {
    const int buf = t % 3;
    const char* Ab = Alds + buf * 32768;
    const char* Bb = Blds + buf * 16384;
    bf16x8 af[4][2], b0[2][2];
    #pragma unroll
    for (int i = 0; i < 4; ++i) {
      int row = wm * 64 + i * 16 + c;
      #pragma unroll
      for (int kk = 0; kk < 2; ++kk)
        af[i][kk] = *(const bf16x8*)(Ab + row * 128 + ((kk * 64 + g * 16) ^ ((row & 7) << 4)));
    }
    #pragma unroll
    for (int j = 0; j < 2; ++j) {
      int row = wn * 64 + j * 16 + c;
      #pragma unroll
      for (int kk = 0; kk < 2; ++kk)
        b0[j][kk] = *(const bf16x8*)(Bb + row * 128 + ((kk * 64 + g * 16) ^ ((row & 7) << 4)));
    }
    if (t + 2 < NTILES) stageA((t + 2) % 3, t + 2);
    __builtin_amdgcn_s_barrier();
    asm volatile("s_waitcnt lgkmcnt(0)" ::: "memory");
    __builtin_amdgcn_sched_barrier(0);
    __builtin_amdgcn_s_setprio(1);
    #pragma unroll
    for (int i = 0; i < 4; ++i)
      #pragma unroll
      for (int j = 0; j < 2; ++j)
        #pragma unroll
        for (int kk = 0; kk < 2; ++kk)
          acc[i][j] = __builtin_amdgcn_mfma_f32_16x16x32_bf16(af[i][kk], b0[j][kk], acc[i][j], 0, 0, 0);
    __builtin_amdgcn_s_setprio(0);
    __builtin_amdgcn_s_barrier();
    bf16x8 b1[2][2];
    #pragma unroll
    for (int j = 0; j < 2; ++j) {
      int row = wn * 64 + (2 + j) * 16 + c;
      #pragma unroll
      for (int kk = 0; kk < 2; ++kk)
        b1[j][kk] = *(const bf16x8*)(Bb + row * 128 + ((kk * 64 + g * 16) ^ ((row & 7) << 4)));
    }
    if (t + 2 < NTILES) stageB((t + 2) % 3, t + 2);
    __builtin_amdgcn_s_barrier();
    asm volatile("s_waitcnt lgkmcnt(0)" ::: "memory");
    __builtin_amdgcn_sched_barrier(0);
    __builtin_amdgcn_s_setprio(1);
    #pragma unroll
    for (int i = 0; i < 4; ++i)
      #pragma unroll
      for (int j = 0; j < 2; ++j)
        #pragma unroll
        for (int kk = 0; kk < 2; ++kk)
          acc[i][j + 2] = __builtin_amdgcn_mfma_f32_16x16x32_bf16(af[i][kk], b1[j][kk], acc[i][j + 2], 0, 0, 0);
    __builtin_amdgcn_s_setprio(0);
    if (t < NTILES - 1) {
      if (t + 2 < NTILES) { asm volatile("s_waitcnt vmcnt(6)" ::: "memory"); }
      else                { asm volatile("s_waitcnt vmcnt(0)" ::: "memory"); }
      __builtin_amdgcn_sched_barrier(0);
      __builtin_amdgcn_s_barrier();
    }
  }
}

// ---- GEMM1: x[M][K] * Wqkv^T[N][K] + bqkv -> scatter Q/K/Vt (Q pre-scaled) ----
__global__ __launch_bounds__(512, 1) void k_gemm1(const unsigned short* __restrict__ A,
                                                  const unsigned short* __restrict__ Bt,
                                                  const float* __restrict__ bias,
                                                  unsigned short* __restrict__ Qb,
                                                  unsigned short* __restrict__ Kb,
                                                  unsigned short* __restrict__ Vt) {
  __shared__ __align__(16) char lds[147456];
  const int n0 = blockIdx.x * 128, m0 = blockIdx.y * 256;
  f32x4 acc[4][4] = {};
  gemm_core((const char*)A + (size_t)m0 * 4096,
            (const char*)Bt + (size_t)n0 * 4096,
            lds, lds + 98304, acc);
  const int lane = threadIdx.x & 63, wave = threadIdx.x >> 6;
  const int g = lane >> 4, c = lane & 15;
  const int wm = wave >> 1, wn = wave & 1;
  const int head = (n0 >> 7) & 15, which = n0 >> 11;
  const float qsc = 0.12751879523263566f;  // (1/sqrt(128)) * log2(e): folded into Q
  #pragma unroll
  for (int i = 0; i < 4; ++i) {
    int rowb = m0 + wm * 64 + i * 16 + g * 4;
    int bb = rowb >> 11, s = rowb & 2047;
    #pragma unroll
    for (int j = 0; j < 4; ++j) {
      int dh = wn * 64 + j * 16 + c;
      float bv = bias[n0 + dh];
      if (which == 2) {
        ushort4 p;
        p.x = f2bf(acc[i][j][0] + bv);
        p.y = f2bf(acc[i][j][1] + bv);
        p.z = f2bf(acc[i][j][2] + bv);
        p.w = f2bf(acc[i][j][3] + bv);
        *(ushort4*)(Vt + ((size_t)(bb * HH + head) * DHH + dh) * SS + s) = p;
      } else {
        float v0 = acc[i][j][0] + bv, v1 = acc[i][j][1] + bv;
        float v2 = acc[i][j][2] + bv, v3 = acc[i][j][3] + bv;
        if (which == 0) { v0 *= qsc; v1 *= qsc; v2 *= qsc; v3 *= qsc; }
        unsigned short* dst = (which == 0 ? Qb : Kb) + ((size_t)(bb * HH + head) * SS + s) * DHH + dh;
        dst[0]       = f2bf(v0);
        dst[DHH]     = f2bf(v1);
        dst[2 * DHH] = f2bf(v2);
        dst[3 * DHH] = f2bf(v3);
      }
    }
  }
}

// ---- GEMM2: O[M][D] * Wproj^T[D][D] + bproj -> f32 out ----
__global__ __launch_bounds__(512, 1) void k_gemm2(const unsigned short* __restrict__ A,
                                                  const unsigned short* __restrict__ Bt,
                                                  const float* __restrict__ bias,
                                                  float* __restrict__ out) {
  __shared__ __align__(16) char lds[147456];
  const int n0 = blockIdx.x * 128, m0 = blockIdx.y * 256;
  f32x4 acc[4][4] = {};
  gemm_core((const char*)A + (size_t)m0 * 4096,
            (const char*)Bt + (size_t)n0 * 4096,
            lds, lds + 98304, acc);
  const int lane = threadIdx.x & 63, wave = threadIdx.x >> 6;
  const int g = lane >> 4, c = lane & 15;
  const int wm = wave >> 1, wn = wave & 1;
  #pragma unroll
  for (int i = 0; i < 4; ++i) {
    int rowb = m0 + wm * 64 + i * 16 + g * 4;
    #pragma unroll
    for (int j = 0; j < 4; ++j) {
      int gcol = n0 + wn * 64 + j * 16 + c;
      float bv = bias[gcol];
      #pragma unroll
      for (int r = 0; r < 4; ++r)
        out[(size_t)(rowb + r) * DD + gcol] = acc[i][j][r] + bv;
    }
  }
}

// ---- flash attention v3: swapped QK^T (lane-local q-row), scalar online-softmax
//      in log2 domain, defer-max, balanced heavy+light block pairing ----
__global__ __launch_bounds__(256, 2) void k_attn(const unsigned short* __restrict__ Qb,
                                                 const unsigned short* __restrict__ Kb,
                                                 const unsigned short* __restrict__ Vt,
                                                 unsigned short* __restrict__ O) {
  __shared__ __align__(16) unsigned short Kt[2][64 * 128];
  __shared__ __align__(16) unsigned short Vs[2][128 * 64];
  __shared__ __align__(16) unsigned short Pl[4][32 * 64];
  // co-resident pair (i, i+256) = same x, y and y+16 -> qtl x and 15-x: uniform 34 tiles/CU
  const int qtl = (blockIdx.y < 16) ? blockIdx.x : (15 - blockIdx.x);
  const int bh = blockIdx.y;
  const int b = bh >> 4, h = bh & 15;
  const int tid = threadIdx.x, wave = tid >> 6, lane = tid & 63;
  const int g = lane >> 4, c = lane & 15;
  const int q0w = qtl * 128 + wave * 32;
  const unsigned short* Qp = Qb + (size_t)bh * SS * DHH;
  const unsigned short* Kp = Kb + (size_t)bh * SS * DHH;
  const unsigned short* Vp = Vt + (size_t)bh * DHH * SS;

  bf16x8 qf[2][4];
  #pragma unroll
  for (int m = 0; m < 2; ++m)
    #pragma unroll
    for (int ks = 0; ks < 4; ++ks)
      qf[m][ks] = *(const bf16x8*)(Qp + (size_t)(q0w + m * 16 + c) * DHH + ks * 32 + g * 8);

  f32x4 acc[2][8] = {};
  float mrow[2] = {-1e30f, -1e30f}, lsum[2] = {0.f, 0.f};

  auto stage = [&](int buf, int kv0) {
    #pragma unroll
    for (int r = 0; r < 4; ++r) {
      int base = r * 4096 + wave * 1024;
      int off = base + (lane << 4);
      { int row = off >> 8; int cb = (off & 255) ^ ((row & 7) << 4);
        gload_lds16((const char*)Kp + (size_t)(kv0 + row) * 256 + cb,
                    (char*)Kt[buf] + base); }
      { int row = off >> 7; int cb = (off & 127) ^ ((row & 7) << 4);
        gload_lds16((const char*)Vp + (size_t)row * (SS * 2) + (size_t)kv0 * 2 + cb,
                    (char*)Vs[buf] + base); }
    }
  };

  const int ntiles = 2 * qtl + 2;
  stage(0, 0);
  __syncthreads();

  for (int t = 0; t < ntiles; ++t) {
    const int cur = t & 1;
    const int kv0 = t * 64;
    if (t + 1 < ntiles) stage(cur ^ 1, kv0 + 64);
    if (kv0 <= q0w + 31) {
      const unsigned short* K_ = Kt[cur];
      const unsigned short* V_ = Vs[cur];
      // QK^T swapped: sa[m][nb] = K_tile * Q^T -> [kv 16nb+4g+r][q 16m+c]
      f32x4 sa[2][4] = {};
      __builtin_amdgcn_s_setprio(1);
      #pragma unroll
      for (int nb = 0; nb < 4; ++nb) {
        const int rk = nb * 16 + c;
        const int swz = (rk & 7) << 4;
        #pragma unroll
        for (int ks = 0; ks < 4; ++ks) {
          bf16x8 kf = *(const bf16x8*)((const char*)K_ + rk * 256 + ((ks * 64 + g * 16) ^ swz));
          sa[0][nb] = __builtin_amdgcn_mfma_f32_16x16x32_bf16(kf, qf[0][ks], sa[0][nb], 0, 0, 0);
          sa[1][nb] = __builtin_amdgcn_mfma_f32_16x16x32_bf16(kf, qf[1][ks], sa[1][nb], 0, 0, 0);
        }
      }
      __builtin_amdgcn_s_setprio(0);
      // per-lane scalar online softmax (log2 domain; Q carries 1/sqrt(dh)*log2e)
      #pragma unroll
      for (int m = 0; m < 2; ++m) {
        const int q = q0w + m * 16 + c;
        float p[4][4];
        float tm = -1e30f;
        #pragma unroll
        for (int nb = 0; nb < 4; ++nb)
          #pragma unroll
          for (int r = 0; r < 4; ++r) {
            float s = sa[m][nb][r];
            if (kv0 + nb * 16 + g * 4 + r > q) s = -1e30f;
            p[nb][r] = s;
            tm = fmaxf(tm, s);
          }
        tm = fmaxf(tm, __shfl_xor(tm, 16, 64));
        tm = fmaxf(tm, __shfl_xor(tm, 32, 64));
        float mr = mrow[m];
        if (__any(tm > mr + 11.0f)) {       // defer-max: rescale only when needed
          float mnew = fmaxf(mr, tm);
          float sf = exp2_hw(mr - mnew);
          lsum[m] *= sf;
          float sfr[4];
          #pragma unroll
          for (int r = 0; r < 4; ++r)        // redistribute q=c -> q=4g+r rows
            sfr[r] = __shfl(sf, 20 * g + r, 64);
          #pragma unroll
          for (int nf = 0; nf < 8; ++nf)
            #pragma unroll
            for (int r = 0; r < 4; ++r) acc[m][nf][r] *= sfr[r];
          mrow[m] = mnew; mr = mnew;
        }
        float rs = 0.f;
        #pragma unroll
        for (int nb = 0; nb < 4; ++nb)
          #pragma unroll
          for (int r = 0; r < 4; ++r) {
            p[nb][r] = exp2_hw(p[nb][r] - mr);
            rs += p[nb][r];
          }
        rs += __shfl_xor(rs, 16, 64);
        rs += __shfl_xor(rs, 32, 64);
        lsum[m] += rs;
        // P^T regs -> Pl[q-local][kv], packed b32 writes, swizzled
        const int rowp = m * 16 + c;
        const int swzp = (rowp & 7) << 4;
        #pragma unroll
        for (int nb = 0; nb < 4; ++nb)
          #pragma unroll
          for (int i2 = 0; i2 < 2; ++i2) {
            u32 w = (u32)f2bf(p[nb][2 * i2]) | ((u32)f2bf(p[nb][2 * i2 + 1]) << 16);
            *(u32*)((char*)Pl[wave] + rowp * 128 + (((nb * 16 + g * 4 + 2 * i2) * 2) ^ swzp)) = w;
          }
      }
      asm volatile("s_waitcnt lgkmcnt(0)" ::: "memory");
      __builtin_amdgcn_sched_barrier(0);
      bf16x8 pf[2][2];
      #pragma unroll
      for (int m = 0; m < 2; ++m)
        #pragma unroll
        for (int c2 = 0; c2 < 2; ++c2) {
          int rowp = m * 16 + c;
          pf[m][c2] = *(const bf16x8*)((const char*)Pl[wave] + rowp * 128 +
                                       ((c2 * 64 + g * 16) ^ ((rowp & 7) << 4)));
        }
      __builtin_amdgcn_s_setprio(1);
      #pragma unroll
      for (int nf = 0; nf < 8; ++nf) {
        const int rv = nf * 16 + c;
        const int swzv = (rv & 7) << 4;
        #pragma unroll
        for (int c2 = 0; c2 < 2; ++c2) {
          bf16x8 vf = *(const bf16x8*)((const char*)V_ + rv * 128 + ((c2 * 64 + g * 16) ^ swzv));
          acc[0][nf] = __builtin_amdgcn_mfma_f32_16x16x32_bf16(pf[0][c2], vf, acc[0][nf], 0, 0, 0);
          acc[1][nf] = __builtin_amdgcn_mfma_f32_16x16x32_bf16(pf[1][c2], vf, acc[1][nf], 0, 0, 0);
        }
      }
      __builtin_amdgcn_s_setprio(0);
    }
    __syncthreads();
  }

  unsigned short* Op = O + (size_t)b * SS * DD + (size_t)h * DHH;
  #pragma unroll
  for (int m = 0; m < 2; ++m) {
    float inv = 1.0f / lsum[m];
    float invr[4];
    #pragma unroll
    for (int r = 0; r < 4; ++r)
      invr[r] = __shfl(inv, 20 * g + r, 64);
    #pragma unroll
    for (int nf = 0; nf < 8; ++nf)
      #pragma unroll
      for (int r = 0; r < 4; ++r) {
        int q = q0w + m * 16 + g * 4 + r;
        Op[(size_t)q * DD + nf * 16 + c] = f2bf(acc[m][nf][r] * invr[r]);
      }
  }
}

extern "C" void kernel_launch(void* const* d_in, const int* in_sizes, int n_in,
                              void* d_out, int out_size, void* d_ws, size_t ws_size,
                              hipStream_t stream) {
  const float* x     = (const float*)d_in[0];
  const float* Wqkv  = (const float*)d_in[1];
  const float* bqkv  = (const float*)d_in[2];
  const float* Wproj = (const float*)d_in[3];
  const float* bproj = (const float*)d_in[4];
  float* out = (float*)d_out;

  char* ws = (char*)d_ws;
  unsigned short* xb  = (unsigned short*)ws; ws += (size_t)MM * DD * 2;
  unsigned short* w1t = (unsigned short*)ws; ws += (size_t)NN1 * DD * 2;
  unsigned short* w2t = (unsigned short*)ws; ws += (size_t)DD * DD * 2;
  unsigned short* Qb  = (unsigned short*)ws; ws += (size_t)BB * HH * SS * DHH * 2;
  unsigned short* Kb  = (unsigned short*)ws; ws += (size_t)BB * HH * SS * DHH * 2;
  unsigned short* Vt  = (unsigned short*)ws; ws += (size_t)BB * HH * SS * DHH * 2;
  unsigned short* Ob  = (unsigned short*)ws; ws += (size_t)MM * DD * 2;

  k_cvt<<<dim3((MM * DD) / 1024), 256, 0, stream>>>(x, xb);
  k_transpose<<<dim3(NN1 / 32, DD / 32), dim3(32, 8), 0, stream>>>(Wqkv, w1t, DD, NN1);
  k_transpose<<<dim3(DD / 32, DD / 32), dim3(32, 8), 0, stream>>>(Wproj, w2t, DD, DD);
  k_gemm1<<<dim3(NN1 / 128, MM / 256), 512, 0, stream>>>(xb, w1t, bqkv, Qb, Kb, Vt);
  k_attn<<<dim3(SS / 128, BB * HH), 256, 0, stream>>>(Qb, Kb, Vt, Ob);
  k_gemm2<<<dim3(DD / 128, MM / 256), 512, 0, stream>>>(Ob, w2t, bproj, out);
}